// Round 11
// baseline (175.871 us; speedup 1.0000x reference)
//
#include <hip/hip_runtime.h>
#include <hip/hip_bf16.h>

// GAT: N=4096 nodes, IN_F=256, H=4 heads, D=64.
// K0 gat_pack : adj (64 MB int) -> bitmask (2 MB). global_load_lds staging
//               (register-free -> immune to the VGPR-32 load serialization),
//               pack from LDS. HBM-bound.
// K1 gat_prep : h = x@W (fp32). 16-row x 64-col tiles, 1024 blocks = 4 waves/SIMD
//               (latency hidden by occupancy, not ILP). siT = <h,a1>*log2e,
//               vv2T = {exp2(sj), exp2(0.2*sj)}, hTf bf16 fragment-major
//               [h][j-chunk][nt][lane] (half-chunk predicated stores), sjm partials.
// K2 gat_attn : masked softmax + PV via mfma_16x16x32_bf16.
//               m_i = leaky(si + max_j sj) upper bound -> pure-sum softmax.
//               64-row tiles x 4 heads x 2 j-splits; 256-j LDS windows double-
//               buffered (32KBx2), staged with contiguous-1KB global_load_lds;
//               masks+vv2 register-prefetched (drained free by window barrier).
// K3 gat_reduce: out = (p0+p1)/(l0+l1).

typedef __bf16 bf16x8 __attribute__((ext_vector_type(8)));
typedef float floatx4 __attribute__((ext_vector_type(4)));

#define LOG2E 1.4426950408889634f
#define NN 4096

__device__ __forceinline__ void gl16(const void* g, void* l) {
  __builtin_amdgcn_global_load_lds(
      (const __attribute__((address_space(1))) unsigned int*)g,
      (__attribute__((address_space(3))) unsigned int*)l, 16, 0, 0);
}

// ---------------- Kernel 0: adj -> bitmask via LDS staging ----------------
// 1024 blocks; block b covers 4 adj rows (4 x 16 KB stages).
__global__ __launch_bounds__(256) void gat_pack(const int* __restrict__ adj,
                                                unsigned short* __restrict__ adjm) {
  __shared__ __align__(16) int buf[4096];   // 16 KB = one adj row
  const int t = threadIdx.x, w = t >> 6, lane = t & 63;
  const int b = blockIdx.x;
  const int* src = adj + (size_t)b * 16384;

  for (int s = 0; s < 4; ++s) {
    const int* sp = src + s * 4096 + w * 1024 + lane * 4;
    int* dp = buf + w * 1024 + lane * 4;
#pragma unroll
    for (int r = 0; r < 4; ++r)
      gl16(sp + r * 256, dp + r * 256);
    __syncthreads();   // drain gl16 -> buf valid
    const int4* rp = (const int4*)(buf + t * 16);
    int4 v0 = rp[0], v1 = rp[1], v2 = rp[2], v3 = rp[3];
    int vs[16] = {v0.x, v0.y, v0.z, v0.w, v1.x, v1.y, v1.z, v1.w,
                  v2.x, v2.y, v2.z, v2.w, v3.x, v3.y, v3.z, v3.w};
    unsigned int m = 0;
#pragma unroll
    for (int q = 0; q < 16; ++q) m |= (vs[q] != 0) ? (1u << q) : 0u;
    adjm[(size_t)(b * 4 + s) * 256 + t] = (unsigned short)m;
    __syncthreads();   // protect buf before restage
  }
}

// ---------------- Kernel 1: h = x@W + per-row scalars + hTf(bf16) ----------------
// 1024 blocks: it = b & 255 (16-row tile), hh = b >> 8. Thread = 1 row x 4 cols.
__global__ __launch_bounds__(256, 4) void gat_prep(
    const float* __restrict__ x, const float* __restrict__ W,
    const float* __restrict__ a1, const float* __restrict__ a2,
    __bf16* __restrict__ hTf, float* __restrict__ siT, float2* __restrict__ vv2T,
    float* __restrict__ sjm) {
  __shared__ float hl[16 * 68];
  __shared__ float sjb[16];
  const int b = blockIdx.x, t = threadIdx.x;
  const int it = b & 255, hh = b >> 8;
  const int i0 = it * 16, c0 = hh * 64;
  const int tr = t >> 4, tc = t & 15;

  float acc[4] = {0.f, 0.f, 0.f, 0.f};
  const float* xr = x + (size_t)(i0 + tr) * 256;
  const float* wp = W + c0 + tc * 4;
#pragma unroll 4
  for (int k = 0; k < 256; k += 4) {
    float4 xv = *(const float4*)(xr + k);
    float4 wv0 = *(const float4*)(wp + (size_t)k * 256);
    float4 wv1 = *(const float4*)(wp + (size_t)(k + 1) * 256);
    float4 wv2 = *(const float4*)(wp + (size_t)(k + 2) * 256);
    float4 wv3 = *(const float4*)(wp + (size_t)(k + 3) * 256);
    acc[0] = fmaf(xv.x, wv0.x, acc[0]);
    acc[1] = fmaf(xv.x, wv0.y, acc[1]);
    acc[2] = fmaf(xv.x, wv0.z, acc[2]);
    acc[3] = fmaf(xv.x, wv0.w, acc[3]);
    acc[0] = fmaf(xv.y, wv1.x, acc[0]);
    acc[1] = fmaf(xv.y, wv1.y, acc[1]);
    acc[2] = fmaf(xv.y, wv1.z, acc[2]);
    acc[3] = fmaf(xv.y, wv1.w, acc[3]);
    acc[0] = fmaf(xv.z, wv2.x, acc[0]);
    acc[1] = fmaf(xv.z, wv2.y, acc[1]);
    acc[2] = fmaf(xv.z, wv2.z, acc[2]);
    acc[3] = fmaf(xv.z, wv2.w, acc[3]);
    acc[0] = fmaf(xv.w, wv3.x, acc[0]);
    acc[1] = fmaf(xv.w, wv3.y, acc[1]);
    acc[2] = fmaf(xv.w, wv3.z, acc[2]);
    acc[3] = fmaf(xv.w, wv3.w, acc[3]);
  }

  float4 a1v = *(const float4*)(a1 + tc * 4);
  float4 a2v = *(const float4*)(a2 + tc * 4);
  float s1 = acc[0]*a1v.x + acc[1]*a1v.y + acc[2]*a1v.z + acc[3]*a1v.w;
  float s2 = acc[0]*a2v.x + acc[1]*a2v.y + acc[2]*a2v.z + acc[3]*a2v.w;
#pragma unroll
  for (int off = 1; off < 16; off <<= 1) {
    s1 += __shfl_xor(s1, off);
    s2 += __shfl_xor(s2, off);
  }
  if (tc == 0) {
    siT[hh * NN + i0 + tr] = s1 * LOG2E;
    float sjs = s2 * LOG2E;
    vv2T[hh * NN + i0 + tr] =
        make_float2(__builtin_amdgcn_exp2f(sjs), __builtin_amdgcn_exp2f(0.2f * sjs));
    sjb[tr] = sjs;
  }
  *(float4*)&hl[tr * 68 + tc * 4] = make_float4(acc[0], acc[1], acc[2], acc[3]);
  __syncthreads();

  if (t < 16) {
    float v = sjb[t];
#pragma unroll
    for (int off = 1; off < 16; off <<= 1) v = fmaxf(v, __shfl_xor(v, off));
    if (t == 0) sjm[it * 4 + hh] = v;
  }

  // fragment-major hTf: chunk c = it>>1, this block owns half (it&1) of it.
  // lane frag: hT[d = nt*16+l16][j = c*32 + quad*8 .. +7]; only quads of our half.
  const int nt = t >> 6, lane = t & 63, quad = lane >> 4, l16 = lane & 15;
  const int c = it >> 1, half = it & 1;
  if ((quad >> 1) == half) {
    const int lr0 = (quad & 1) * 8;   // local row base within the 16-row tile
    bf16x8 h0;
#pragma unroll
    for (int jj = 0; jj < 8; ++jj)
      h0[jj] = (__bf16)hl[(lr0 + jj) * 68 + nt * 16 + l16];
    *(bf16x8*)((char*)hTf + ((((size_t)hh * 128 + c) * 4 + nt) << 10) + (lane << 4)) = h0;
  }
}

// ---------------- Kernel 2: masked softmax + PV (MFMA) ----------------
// grid (64 i-tiles of 64 rows, 4 heads, 2 j-splits), 256 threads = 4 waves;
// wave w owns j-offset w*64 within each 256-j window; 8 windows per block.
__global__ __launch_bounds__(256, 2) void gat_attn(
    const __bf16* __restrict__ hTf, const float* __restrict__ siT,
    const float2* __restrict__ vv2T, const float* __restrict__ sjm,
    const unsigned int* __restrict__ adjw,
    float* __restrict__ pacc, float* __restrict__ pl) {
  // LDS: hT buf0 [0,32768) | hT buf1 [32768,65536)
  // epilogue alias: accs f32[2][64][68] @0 (34816 B), lsum f32[2][64] @34816
  __shared__ __align__(16) char lds[65536];
  const int t = threadIdx.x;
  const int w = t >> 6, lane = t & 63, quad = lane >> 4, l16 = lane & 15;
  const int i0 = blockIdx.x * 64, hh = blockIdx.y, s = blockIdx.z;
  const int jbeg = s * 2048;

  // staging source: this wave's first chunk (chunk = 32 j = 4 KB), + lane*16
  const char* hsrc = (const char*)hTf +
      (((size_t)hh * 128 + (jbeg >> 5) + w * 2) << 12) + (lane << 4);
  const float2* vw = vv2T + (size_t)hh * NN + jbeg + w * 64;

  const unsigned int* mp[4];
#pragma unroll
  for (int mt = 0; mt < 4; ++mt)
    mp[mt] = adjw + (size_t)(i0 + mt * 16 + l16) * 128 + (jbeg >> 5) + w * 2;

  // ---- prefetch window 0: masks + vv2 (regs), hT (LDS buf0) ----
  uint2 mc[4], mn[4];
  float4 qc[2][4], qn[2][4];
#pragma unroll
  for (int mt = 0; mt < 4; ++mt) mc[mt] = *(const uint2*)mp[mt];
#pragma unroll
  for (int k = 0; k < 2; ++k) {
    const float4* qp = (const float4*)(vw + k * 32 + quad * 8);
#pragma unroll
    for (int c = 0; c < 4; ++c) qc[k][c] = qp[c];
  }
#pragma unroll
  for (int k = 0; k < 2; ++k)
#pragma unroll
    for (int nt = 0; nt < 4; ++nt)
      gl16(hsrc + ((k * 4 + nt) << 10),
           lds + (((w * 8 + k * 4 + nt) << 10) + (lane << 4)));

  // ---- per-row constants (overlaps staging); 256 sjm partials ----
  float vv = fmaxf(fmaxf(sjm[lane * 4 + hh], sjm[(lane + 64) * 4 + hh]),
                   fmaxf(sjm[(lane + 128) * 4 + hh], sjm[(lane + 192) * 4 + hh]));
#pragma unroll
  for (int off = 1; off < 64; off <<= 1) vv = fmaxf(vv, __shfl_xor(vv, off));
  float u[4], u2[4];
#pragma unroll
  for (int mt = 0; mt < 4; ++mt) {
    float sis = siT[hh * NN + i0 + mt * 16 + l16];
    float tt = sis + vv;
    float m = fmaxf(tt, 0.2f * tt);   // leaky monotone -> valid row-max upper bound
    u[mt] = __builtin_amdgcn_exp2f(sis - m);
    u2[mt] = __builtin_amdgcn_exp2f(0.2f * sis - m);
  }

  bf16x8 ones;
#pragma unroll
  for (int ii = 0; ii < 8; ++ii) ones[ii] = (__bf16)1.0f;

  floatx4 zv = {0.f, 0.f, 0.f, 0.f};
  floatx4 acc[4][4], lacc[4];
#pragma unroll
  for (int mt = 0; mt < 4; ++mt) {
    lacc[mt] = zv;
#pragma unroll
    for (int nt = 0; nt < 4; ++nt) acc[mt][nt] = zv;
  }

  __syncthreads();   // window 0 staged

  for (int win = 0; win < 8; ++win) {
    const int p = win & 1;
    const char* hb = lds + p * 32768;

    if (win + 1 < 8) {  // prefetch next window: regs first, then LDS staging
#pragma unroll
      for (int mt = 0; mt < 4; ++mt)
        mn[mt] = *(const uint2*)(mp[mt] + (win + 1) * 8);
#pragma unroll
      for (int k = 0; k < 2; ++k) {
        const float4* qp = (const float4*)(vw + (win + 1) * 256 + k * 32 + quad * 8);
#pragma unroll
        for (int c = 0; c < 4; ++c) qn[k][c] = qp[c];
      }
      char* hbn = lds + (p ^ 1) * 32768;
      const char* hs = hsrc + (win + 1) * 32768;
#pragma unroll
      for (int k = 0; k < 2; ++k)
#pragma unroll
        for (int nt = 0; nt < 4; ++nt)
          gl16(hs + ((k * 4 + nt) << 10),
               hbn + (((w * 8 + k * 4 + nt) << 10) + (lane << 4)));
    }

#pragma unroll
    for (int k = 0; k < 2; ++k) {
      bf16x8 bfr[4];
#pragma unroll
      for (int nt = 0; nt < 4; ++nt)
        bfr[nt] = *(const bf16x8*)(hb + ((w * 8 + k * 4 + nt) << 10) + (lane << 4));
#pragma unroll
      for (int mt = 0; mt < 4; ++mt) {
        unsigned int m8 = (k ? mc[mt].y : mc[mt].x) >> (quad * 8);
        bf16x8 af;
#pragma unroll
        for (int c = 0; c < 4; ++c) {
          float p0 = fmaxf(u[mt] * qc[k][c].x, u2[mt] * qc[k][c].y);
          float p1 = fmaxf(u[mt] * qc[k][c].z, u2[mt] * qc[k][c].w);
          // sign-extended 1-bit extract -> bitwise AND (2 VALU, no cmp/cndmask)
          int b0 = ((int)(m8 << (31 - 2 * c))) >> 31;
          int b1 = ((int)(m8 << (30 - 2 * c))) >> 31;
          af[2 * c]     = (__bf16)__uint_as_float(__float_as_uint(p0) & (unsigned)b0);
          af[2 * c + 1] = (__bf16)__uint_as_float(__float_as_uint(p1) & (unsigned)b1);
        }
#pragma unroll
        for (int nt = 0; nt < 4; ++nt)
          acc[mt][nt] = __builtin_amdgcn_mfma_f32_16x16x32_bf16(af, bfr[nt],
                                                                acc[mt][nt], 0, 0, 0);
        lacc[mt] = __builtin_amdgcn_mfma_f32_16x16x32_bf16(af, ones, lacc[mt], 0, 0, 0);
      }
    }
#pragma unroll
    for (int mt = 0; mt < 4; ++mt) mc[mt] = mn[mt];
#pragma unroll
    for (int k = 0; k < 2; ++k)
#pragma unroll
      for (int c = 0; c < 4; ++c) qc[k][c] = qn[k][c];
    __syncthreads();
  }

  // epilogue: combine the 4 j-split waves in LDS (aliases dead staging bufs)
  float* accs = (float*)lds;             // [2][64][68]
  float* lsum = (float*)(lds + 34816);   // [2][64]
  // C layout: row = mt*16 + quad*4 + reg, col = nt*16 + l16
  if (w < 2) {
#pragma unroll
    for (int mt = 0; mt < 4; ++mt)
#pragma unroll
      for (int reg = 0; reg < 4; ++reg) {
        int row = mt * 16 + quad * 4 + reg;
        float* ap = accs + (w * 64 + row) * 68;
#pragma unroll
        for (int nt = 0; nt < 4; ++nt)
          ap[nt * 16 + l16] = acc[mt][nt][reg];
        if (l16 == 0) lsum[w * 64 + row] = lacc[mt][reg];
      }
  }
  __syncthreads();
  if (w >= 2) {
    const int bb = w - 2;
#pragma unroll
    for (int mt = 0; mt < 4; ++mt)
#pragma unroll
      for (int reg = 0; reg < 4; ++reg) {
        int row = mt * 16 + quad * 4 + reg;
        float* ap = accs + (bb * 64 + row) * 68;
#pragma unroll
        for (int nt = 0; nt < 4; ++nt)
          ap[nt * 16 + l16] += acc[mt][nt][reg];
        if (l16 == 0) lsum[bb * 64 + row] += lacc[mt][reg];
      }
  }
  __syncthreads();

  // write partials: r = t>>2 (64 rows), cbase = (t&3)*16 (16 cols per thread)
  const int r = t >> 2, cb = (t & 3) * 16;
  float* op = pacc + (size_t)s * NN * 256 + (size_t)(i0 + r) * 256 + hh * 64 + cb;
#pragma unroll
  for (int c4 = 0; c4 < 4; ++c4) {
    int c = cb + c4 * 4;
    float4 o;
    o.x = accs[r * 68 + c + 0] + accs[(64 + r) * 68 + c + 0];
    o.y = accs[r * 68 + c + 1] + accs[(64 + r) * 68 + c + 1];
    o.z = accs[r * 68 + c + 2] + accs[(64 + r) * 68 + c + 2];
    o.w = accs[r * 68 + c + 3] + accs[(64 + r) * 68 + c + 3];
    *(float4*)(op + c4 * 4) = o;
  }
  if (t < 64)
    pl[(size_t)s * NN * 4 + (i0 + t) * 4 + hh] = lsum[t] + lsum[64 + t];
}

// ---------------- Kernel 3: combine j-splits + normalize ----------------
__global__ __launch_bounds__(256) void gat_reduce(
    const float* __restrict__ pacc, const float* __restrict__ pl,
    float* __restrict__ out) {
  const int e4 = blockIdx.x * 256 + threadIdx.x;
  const int e = e4 * 4;                 // e = i*256 + h*64 + d
  const int i = e >> 8;
  const int h = (e & 255) >> 6;
  float4 a0 = *(const float4*)(pacc + e);
  float4 a1 = *(const float4*)(pacc + (size_t)NN * 256 + e);
  float l = pl[i * 4 + h] + pl[(size_t)NN * 4 + i * 4 + h];
  float inv = 1.0f / l;
  *(float4*)(out + e) = make_float4((a0.x + a1.x) * inv, (a0.y + a1.y) * inv,
                                    (a0.z + a1.z) * inv, (a0.w + a1.w) * inv);
}

extern "C" void kernel_launch(void* const* d_in, const int* in_sizes, int n_in,
                              void* d_out, int out_size, void* d_ws, size_t ws_size,
                              hipStream_t stream) {
  const float* x  = (const float*)d_in[0];
  const int*   adj = (const int*)d_in[1];
  const float* W  = (const float*)d_in[2];
  const float* a1 = (const float*)d_in[3];
  const float* a2 = (const float*)d_in[4];
  float* out = (float*)d_out;
  char* ws = (char*)d_ws;

  // ws layout (bytes):
  //   hTf  bf16   [4][128][4][1024B] @ 0   (2 MiB, fragment-major)
  //   siT  f32    [4][4096]     @ 2097152  (64 KiB)
  //   vv2T f32x2  [4][4096]     @ 2162688  (128 KiB)
  //   sjm  f32    [256][4]      @ 2293760  (4 KiB)
  //   adjb u16    [4096][256]   @ 2297856  (2 MiB bitmask)
  //   pacc f32    [2][4096][256]@ 4395008  (8 MiB)
  //   pl   f32    [2][4096][4]  @ 12783616 (128 KiB)
  __bf16* hTf  = (__bf16*)ws;
  float*  siT  = (float*)(ws + 2097152);
  float2* vv2T = (float2*)(ws + 2162688);
  float*  sjm  = (float*)(ws + 2293760);
  unsigned char* adjb = (unsigned char*)(ws + 2297856);
  float*  pacc = (float*)(ws + 4395008);
  float*  pl   = (float*)(ws + 12783616);

  gat_pack<<<1024, 256, 0, stream>>>(adj, (unsigned short*)adjb);
  gat_prep<<<1024, 256, 0, stream>>>(x, W, a1, a2, hTf, siT, vv2T, sjm);
  gat_attn<<<dim3(64, 4, 2), 256, 0, stream>>>(hTf, siT, vv2T, sjm,
                                               (const unsigned int*)adjb, pacc, pl);
  gat_reduce<<<1024, 256, 0, stream>>>(pacc, pl, out);
}

// Round 12
// 141.304 us; speedup vs baseline: 1.2446x; 1.2446x over previous
//
#include <hip/hip_runtime.h>
#include <hip/hip_bf16.h>

// GAT: N=4096 nodes, IN_F=256, H=4 heads, D=64.
// K0 gat_pack : blocks [0,2048): adj (64 MB) -> bitmask (2 MB) via gl16 LDS staging.
//               blocks [2048,2064): W (fp32 [k][c]) -> WT bf16 [c][k] (128 KB).
//               blocks [2064,2320): x (fp32) -> xb bf16 row-major (2 MB).
// K1 gat_prep : h = xb@W via mfma_16x16x32_bf16 (fp32 acc). 64-row x 64-col blocks;
//               A/B fragments staged full-K into LDS with per-lane-gather gl16 in
//               MFMA lane order. si/sj fp32 from acc; hTf bf16 fragment-major.
// K2 gat_attn : masked softmax + PV via MFMA (unchanged; 64 sjm partials).
// K3 gat_reduce: out = (p0+p1)/(l0+l1).

typedef __bf16 bf16x8 __attribute__((ext_vector_type(8)));
typedef __bf16 bf16x4 __attribute__((ext_vector_type(4)));
typedef float floatx4 __attribute__((ext_vector_type(4)));

#define LOG2E 1.4426950408889634f
#define NN 4096

__device__ __forceinline__ void gl16(const void* g, void* l) {
  __builtin_amdgcn_global_load_lds(
      (const __attribute__((address_space(1))) unsigned int*)g,
      (__attribute__((address_space(3))) unsigned int*)l, 16, 0, 0);
}

// ---------------- Kernel 0: pack + dtype conversions ----------------
__global__ __launch_bounds__(256) void gat_pack(
    const int* __restrict__ adj, const float* __restrict__ x,
    const float* __restrict__ W, unsigned short* __restrict__ adjm,
    __bf16* __restrict__ xb, __bf16* __restrict__ WT) {
  __shared__ __align__(16) int buf[4096];   // 16 KB
  const int b = blockIdx.x, t = threadIdx.x;
  const int w = t >> 6, lane = t & 63;

  if (b < 2048) {  // ---- adj -> bitmask, 2 rows per block ----
    for (int s = 0; s < 2; ++s) {
      const int row = b * 2 + s;
      const int* sp = adj + (size_t)row * 4096 + w * 1024 + lane * 4;
      int* dp = buf + w * 1024 + lane * 4;
#pragma unroll
      for (int r = 0; r < 4; ++r) gl16(sp + r * 256, dp + r * 256);
      __syncthreads();   // drain gl16 -> buf valid
      const int4* rp = (const int4*)(buf + t * 16);
      int4 v0 = rp[0], v1 = rp[1], v2 = rp[2], v3 = rp[3];
      int vs[16] = {v0.x, v0.y, v0.z, v0.w, v1.x, v1.y, v1.z, v1.w,
                    v2.x, v2.y, v2.z, v2.w, v3.x, v3.y, v3.z, v3.w};
      unsigned int m = 0;
#pragma unroll
      for (int q = 0; q < 16; ++q) m |= (vs[q] != 0) ? (1u << q) : 0u;
      adjm[(size_t)row * 256 + t] = (unsigned short)m;
      __syncthreads();   // protect buf before restage
    }
    return;
  }

  if (b < 2064) {  // ---- W -> WT bf16 ([c][k]) ----
    const int k0 = (b - 2048) * 16;
    const float* sp = W + (size_t)k0 * 256 + w * 1024 + lane * 4;
    int* dp = buf + w * 1024 + lane * 4;
#pragma unroll
    for (int r = 0; r < 4; ++r) gl16(sp + r * 256, dp + r * 256);
    __syncthreads();
    const float* wl = (const float*)buf;
    bf16x8 o0, o1;
#pragma unroll
    for (int k = 0; k < 8; ++k) o0[k] = (__bf16)wl[k * 256 + t];
#pragma unroll
    for (int k = 0; k < 8; ++k) o1[k] = (__bf16)wl[(8 + k) * 256 + t];
    __bf16* op = WT + (size_t)t * 256 + k0;
    *(bf16x8*)op = o0;
    *(bf16x8*)(op + 8) = o1;
    return;
  }

  // ---- x -> xb bf16 (row-major) ----
  const int bi = b - 2064;
  const float4* x4 = (const float4*)x;
#pragma unroll
  for (int it = 0; it < 4; ++it) {
    int g = it * 65536 + bi * 256 + t;   // float4 index, 256K total
    float4 f = x4[g];
    bf16x4 o = {(__bf16)f.x, (__bf16)f.y, (__bf16)f.z, (__bf16)f.w};
    *(bf16x4*)(xb + (size_t)g * 4) = o;
  }
}

// ---------------- Kernel 1: h = xb@W (MFMA) + scalars + hTf ----------------
// grid 256: it = b&63 (64-row tile), hh = b>>6. 256 threads = 4 waves.
__global__ __launch_bounds__(256, 2) void gat_prep(
    const __bf16* __restrict__ xb, const __bf16* __restrict__ WT,
    const float* __restrict__ a1, const float* __restrict__ a2,
    __bf16* __restrict__ hTf, float* __restrict__ siT, float2* __restrict__ vv2T,
    float* __restrict__ sjm) {
  // LDS: A-frags [0,32768) slot ((mt*8+kw)<<10), B-frags [32768,65536).
  // epilogue alias: hl f32[64][68] @0, sjb f32[64] @20480
  __shared__ __align__(16) char plds[65536];
  const int b = blockIdx.x, t = threadIdx.x;
  const int it = b & 63, hh = b >> 6;
  const int i0 = it * 64, c0 = hh * 64;
  const int w = t >> 6, lane = t & 63, quad = lane >> 4, l16 = lane & 15;

  // stage full-K fragments: wave w = A subtile mt=w (16 rows) + B subtile nt=w.
  // lane src: [m|n = l16][k = kw*32 + quad*8 .. +7]  (16 B per lane, per-lane gather)
  const __bf16* asrc = xb + ((size_t)(i0 + w * 16 + l16) << 8) + quad * 8;
  const __bf16* bsrc = WT + ((size_t)(c0 + w * 16 + l16) << 8) + quad * 8;
#pragma unroll
  for (int kw = 0; kw < 8; ++kw) {
    gl16(asrc + kw * 32, plds + (((w * 8 + kw) << 10) + (lane << 4)));
    gl16(bsrc + kw * 32, plds + 32768 + (((w * 8 + kw) << 10) + (lane << 4)));
  }

  float a1v[4], a2v[4];
#pragma unroll
  for (int nt = 0; nt < 4; ++nt) {
    a1v[nt] = a1[nt * 16 + l16];
    a2v[nt] = a2[nt * 16 + l16];
  }
  __syncthreads();   // fragments staged

  floatx4 zv = {0.f, 0.f, 0.f, 0.f};
  floatx4 acc[4] = {zv, zv, zv, zv};
#pragma unroll
  for (int kw = 0; kw < 8; ++kw) {
    bf16x8 af = *(const bf16x8*)(plds + (((w * 8 + kw) << 10) + (lane << 4)));
#pragma unroll
    for (int nt = 0; nt < 4; ++nt) {
      bf16x8 bfr = *(const bf16x8*)(plds + 32768 + (((nt * 8 + kw) << 10) + (lane << 4)));
      acc[nt] = __builtin_amdgcn_mfma_f32_16x16x32_bf16(af, bfr, acc[nt], 0, 0, 0);
    }
  }
  __syncthreads();   // all LDS reads done; reuse plds for epilogue

  // C layout: row = w*16 + quad*4 + reg, col = nt*16 + l16
  float* hl = (float*)plds;              // [64][68]
  float* sjb = (float*)(plds + 20480);   // [64]
#pragma unroll
  for (int reg = 0; reg < 4; ++reg) {
    const int row = w * 16 + quad * 4 + reg;
#pragma unroll
    for (int nt = 0; nt < 4; ++nt) hl[row * 68 + nt * 16 + l16] = acc[nt][reg];
    float s1 = acc[0][reg] * a1v[0] + acc[1][reg] * a1v[1] +
               acc[2][reg] * a1v[2] + acc[3][reg] * a1v[3];
    float s2 = acc[0][reg] * a2v[0] + acc[1][reg] * a2v[1] +
               acc[2][reg] * a2v[2] + acc[3][reg] * a2v[3];
#pragma unroll
    for (int off = 1; off < 16; off <<= 1) {
      s1 += __shfl_xor(s1, off);
      s2 += __shfl_xor(s2, off);
    }
    if (l16 == 0) {
      siT[hh * NN + i0 + row] = s1 * LOG2E;
      float sjs = s2 * LOG2E;
      vv2T[hh * NN + i0 + row] =
          make_float2(__builtin_amdgcn_exp2f(sjs), __builtin_amdgcn_exp2f(0.2f * sjs));
      sjb[row] = sjs;
    }
  }
  __syncthreads();

  if (t < 64) {  // block sj-max partial (64 tiles -> sjm[64][4])
    float v = sjb[t];
#pragma unroll
    for (int off = 1; off < 64; off <<= 1) v = fmaxf(v, __shfl_xor(v, off));
    if (t == 0) sjm[it * 4 + hh] = v;
  }

  // fragment-major hTf: 2 chunks of 32 j; lane frag hT[d=nt2*16+l16][j=quad*8..+7]
  const int nt2 = t >> 6;
#pragma unroll
  for (int ch = 0; ch < 2; ++ch) {
    bf16x8 h0;
#pragma unroll
    for (int jj = 0; jj < 8; ++jj)
      h0[jj] = (__bf16)hl[(ch * 32 + quad * 8 + jj) * 68 + nt2 * 16 + l16];
    *(bf16x8*)((char*)hTf +
               ((((size_t)hh * 128 + it * 2 + ch) * 4 + nt2) << 10) + (lane << 4)) = h0;
  }
}

// ---------------- Kernel 2: masked softmax + PV (MFMA) ----------------
// grid (64 i-tiles of 64 rows, 4 heads, 2 j-splits), 256 threads = 4 waves;
// wave w owns j-offset w*64 within each 256-j window; 8 windows per block.
__global__ __launch_bounds__(256, 2) void gat_attn(
    const __bf16* __restrict__ hTf, const float* __restrict__ siT,
    const float2* __restrict__ vv2T, const float* __restrict__ sjm,
    const unsigned int* __restrict__ adjw,
    float* __restrict__ pacc, float* __restrict__ pl) {
  // LDS: hT buf0 [0,32768) | hT buf1 [32768,65536)
  // epilogue alias: accs f32[2][64][68] @0 (34816 B), lsum f32[2][64] @34816
  __shared__ __align__(16) char lds[65536];
  const int t = threadIdx.x;
  const int w = t >> 6, lane = t & 63, quad = lane >> 4, l16 = lane & 15;
  const int i0 = blockIdx.x * 64, hh = blockIdx.y, s = blockIdx.z;
  const int jbeg = s * 2048;

  // staging source: this wave's first chunk (chunk = 32 j = 4 KB), + lane*16
  const char* hsrc = (const char*)hTf +
      (((size_t)hh * 128 + (jbeg >> 5) + w * 2) << 12) + (lane << 4);
  const float2* vw = vv2T + (size_t)hh * NN + jbeg + w * 64;

  const unsigned int* mp[4];
#pragma unroll
  for (int mt = 0; mt < 4; ++mt)
    mp[mt] = adjw + (size_t)(i0 + mt * 16 + l16) * 128 + (jbeg >> 5) + w * 2;

  // ---- prefetch window 0: masks + vv2 (regs), hT (LDS buf0) ----
  uint2 mc[4], mn[4];
  float4 qc[2][4], qn[2][4];
#pragma unroll
  for (int mt = 0; mt < 4; ++mt) mc[mt] = *(const uint2*)mp[mt];
#pragma unroll
  for (int k = 0; k < 2; ++k) {
    const float4* qp = (const float4*)(vw + k * 32 + quad * 8);
#pragma unroll
    for (int c = 0; c < 4; ++c) qc[k][c] = qp[c];
  }
#pragma unroll
  for (int k = 0; k < 2; ++k)
#pragma unroll
    for (int nt = 0; nt < 4; ++nt)
      gl16(hsrc + ((k * 4 + nt) << 10),
           lds + (((w * 8 + k * 4 + nt) << 10) + (lane << 4)));

  // ---- per-row constants (overlaps staging); 64 sjm partials ----
  float vv = sjm[lane * 4 + hh];
#pragma unroll
  for (int off = 1; off < 64; off <<= 1) vv = fmaxf(vv, __shfl_xor(vv, off));
  float u[4], u2[4];
#pragma unroll
  for (int mt = 0; mt < 4; ++mt) {
    float sis = siT[hh * NN + i0 + mt * 16 + l16];
    float tt = sis + vv;
    float m = fmaxf(tt, 0.2f * tt);   // leaky monotone -> valid row-max upper bound
    u[mt] = __builtin_amdgcn_exp2f(sis - m);
    u2[mt] = __builtin_amdgcn_exp2f(0.2f * sis - m);
  }

  bf16x8 ones;
#pragma unroll
  for (int ii = 0; ii < 8; ++ii) ones[ii] = (__bf16)1.0f;

  floatx4 zv = {0.f, 0.f, 0.f, 0.f};
  floatx4 acc[4][4], lacc[4];
#pragma unroll
  for (int mt = 0; mt < 4; ++mt) {
    lacc[mt] = zv;
#pragma unroll
    for (int nt = 0; nt < 4; ++nt) acc[mt][nt] = zv;
  }

  __syncthreads();   // window 0 staged

  for (int win = 0; win < 8; ++win) {
    const int p = win & 1;
    const char* hb = lds + p * 32768;

    if (win + 1 < 8) {  // prefetch next window: regs first, then LDS staging
#pragma unroll
      for (int mt = 0; mt < 4; ++mt)
        mn[mt] = *(const uint2*)(mp[mt] + (win + 1) * 8);
#pragma unroll
      for (int k = 0; k < 2; ++k) {
        const float4* qp = (const float4*)(vw + (win + 1) * 256 + k * 32 + quad * 8);
#pragma unroll
        for (int c = 0; c < 4; ++c) qn[k][c] = qp[c];
      }
      char* hbn = lds + (p ^ 1) * 32768;
      const char* hs = hsrc + (win + 1) * 32768;
#pragma unroll
      for (int k = 0; k < 2; ++k)
#pragma unroll
        for (int nt = 0; nt < 4; ++nt)
          gl16(hs + ((k * 4 + nt) << 10),
               hbn + (((w * 8 + k * 4 + nt) << 10) + (lane << 4)));
    }

#pragma unroll
    for (int k = 0; k < 2; ++k) {
      bf16x8 bfr[4];
#pragma unroll
      for (int nt = 0; nt < 4; ++nt)
        bfr[nt] = *(const bf16x8*)(hb + ((w * 8 + k * 4 + nt) << 10) + (lane << 4));
#pragma unroll
      for (int mt = 0; mt < 4; ++mt) {
        unsigned int m8 = (k ? mc[mt].y : mc[mt].x) >> (quad * 8);
        bf16x8 af;
#pragma unroll
        for (int c = 0; c < 4; ++c) {
          float p0 = fmaxf(u[mt] * qc[k][c].x, u2[mt] * qc[k][c].y);
          float p1 = fmaxf(u[mt] * qc[k][c].z, u2[mt] * qc[k][c].w);
          // sign-extended 1-bit extract -> bitwise AND (2 VALU, no cmp/cndmask)
          int b0 = ((int)(m8 << (31 - 2 * c))) >> 31;
          int b1 = ((int)(m8 << (30 - 2 * c))) >> 31;
          af[2 * c]     = (__bf16)__uint_as_float(__float_as_uint(p0) & (unsigned)b0);
          af[2 * c + 1] = (__bf16)__uint_as_float(__float_as_uint(p1) & (unsigned)b1);
        }
#pragma unroll
        for (int nt = 0; nt < 4; ++nt)
          acc[mt][nt] = __builtin_amdgcn_mfma_f32_16x16x32_bf16(af, bfr[nt],
                                                                acc[mt][nt], 0, 0, 0);
        lacc[mt] = __builtin_amdgcn_mfma_f32_16x16x32_bf16(af, ones, lacc[mt], 0, 0, 0);
      }
    }
#pragma unroll
    for (int mt = 0; mt < 4; ++mt) mc[mt] = mn[mt];
#pragma unroll
    for (int k = 0; k < 2; ++k)
#pragma unroll
      for (int c = 0; c < 4; ++c) qc[k][c] = qn[k][c];
    __syncthreads();
  }

  // epilogue: combine the 4 j-split waves in LDS (aliases dead staging bufs)
  float* accs = (float*)lds;             // [2][64][68]
  float* lsum = (float*)(lds + 34816);   // [2][64]
  // C layout: row = mt*16 + quad*4 + reg, col = nt*16 + l16
  if (w < 2) {
#pragma unroll
    for (int mt = 0; mt < 4; ++mt)
#pragma unroll
      for (int reg = 0; reg < 4; ++reg) {
        int row = mt * 16 + quad * 4 + reg;
        float* ap = accs + (w * 64 + row) * 68;
#pragma unroll
        for (int nt = 0; nt < 4; ++nt)
          ap[nt * 16 + l16] = acc[mt][nt][reg];
        if (l16 == 0) lsum[w * 64 + row] = lacc[mt][reg];
      }
  }
  __syncthreads();
  if (w >= 2) {
    const int bb = w - 2;
#pragma unroll
    for (int mt = 0; mt < 4; ++mt)
#pragma unroll
      for (int reg = 0; reg < 4; ++reg) {
        int row = mt * 16 + quad * 4 + reg;
        float* ap = accs + (bb * 64 + row) * 68;
#pragma unroll
        for (int nt = 0; nt < 4; ++nt)
          ap[nt * 16 + l16] += acc[mt][nt][reg];
        if (l16 == 0) lsum[bb * 64 + row] += lacc[mt][reg];
      }
  }
  __syncthreads();

  // write partials: r = t>>2 (64 rows), cbase = (t&3)*16 (16 cols per thread)
  const int r = t >> 2, cb = (t & 3) * 16;
  float* op = pacc + (size_t)s * NN * 256 + (size_t)(i0 + r) * 256 + hh * 64 + cb;
#pragma unroll
  for (int c4 = 0; c4 < 4; ++c4) {
    int c = cb + c4 * 4;
    float4 o;
    o.x = accs[r * 68 + c + 0] + accs[(64 + r) * 68 + c + 0];
    o.y = accs[r * 68 + c + 1] + accs[(64 + r) * 68 + c + 1];
    o.z = accs[r * 68 + c + 2] + accs[(64 + r) * 68 + c + 2];
    o.w = accs[r * 68 + c + 3] + accs[(64 + r) * 68 + c + 3];
    *(float4*)(op + c4 * 4) = o;
  }
  if (t < 64)
    pl[(size_t)s * NN * 4 + (i0 + t) * 4 + hh] = lsum[t] + lsum[64 + t];
}

// ---------------- Kernel 3: combine j-splits + normalize ----------------
__global__ __launch_bounds__(256) void gat_reduce(
    const float* __restrict__ pacc, const float* __restrict__ pl,
    float* __restrict__ out) {
  const int e4 = blockIdx.x * 256 + threadIdx.x;
  const int e = e4 * 4;                 // e = i*256 + h*64 + d
  const int i = e >> 8;
  const int h = (e & 255) >> 6;
  float4 a0 = *(const float4*)(pacc + e);
  float4 a1 = *(const float4*)(pacc + (size_t)NN * 256 + e);
  float l = pl[i * 4 + h] + pl[(size_t)NN * 4 + i * 4 + h];
  float inv = 1.0f / l;
  *(float4*)(out + e) = make_float4((a0.x + a1.x) * inv, (a0.y + a1.y) * inv,
                                    (a0.z + a1.z) * inv, (a0.w + a1.w) * inv);
}

extern "C" void kernel_launch(void* const* d_in, const int* in_sizes, int n_in,
                              void* d_out, int out_size, void* d_ws, size_t ws_size,
                              hipStream_t stream) {
  const float* x  = (const float*)d_in[0];
  const int*   adj = (const int*)d_in[1];
  const float* W  = (const float*)d_in[2];
  const float* a1 = (const float*)d_in[3];
  const float* a2 = (const float*)d_in[4];
  float* out = (float*)d_out;
  char* ws = (char*)d_ws;

  // ws layout (bytes):
  //   hTf  bf16   [4][128][4][1024B] @ 0   (2 MiB, fragment-major)
  //   siT  f32    [4][4096]     @ 2097152  (64 KiB)
  //   vv2T f32x2  [4][4096]     @ 2162688  (128 KiB)
  //   sjm  f32    [64][4]       @ 2293760  (1 KiB)
  //   adjb u16    [4096][256]   @ 2297856  (2 MiB bitmask)
  //   xb   bf16   [4096][256]   @ 4395008  (2 MiB)
  //   WT   bf16   [256][256]    @ 6492160  (128 KiB)
  //   pacc f32    [2][4096][256]@ 6623232  (8 MiB)
  //   pl   f32    [2][4096][4]  @ 15011840 (128 KiB)
  __bf16* hTf  = (__bf16*)ws;
  float*  siT  = (float*)(ws + 2097152);
  float2* vv2T = (float2*)(ws + 2162688);
  float*  sjm  = (float*)(ws + 2293760);
  unsigned short* adjb = (unsigned short*)(ws + 2297856);
  __bf16* xb   = (__bf16*)(ws + 4395008);
  __bf16* WT   = (__bf16*)(ws + 6492160);
  float*  pacc = (float*)(ws + 6623232);
  float*  pl   = (float*)(ws + 15011840);

  gat_pack<<<2320, 256, 0, stream>>>(adj, x, W, adjb, xb, WT);
  gat_prep<<<256, 256, 0, stream>>>(xb, WT, a1, a2, hTf, siT, vv2T, sjm);
  gat_attn<<<dim3(64, 4, 2), 256, 0, stream>>>(hTf, siT, vv2T, sjm,
                                               (const unsigned int*)adjb, pacc, pl);
  gat_reduce<<<1024, 256, 0, stream>>>(pacc, pl, out);
}